// Round 5
// baseline (1018.401 us; speedup 1.0000x reference)
//
#include <hip/hip_runtime.h>
#include <hip/hip_bf16.h>

typedef _Float16 f16;
typedef _Float16 f16x8 __attribute__((ext_vector_type(8)));
typedef _Float16 f16x4 __attribute__((ext_vector_type(4)));
typedef _Float16 f16x2 __attribute__((ext_vector_type(2)));
typedef float f32x4 __attribute__((ext_vector_type(4)));
typedef unsigned long long ull;

#define B_ 64
#define T_ 32
#define L_ 49
#define F_ 512
#define H_ 512
#define A_ 256
#define E_ 256
#define V_ 32000
#define G4 2048    // 4*H
#define NC 2304    // G4 + A (W_hh | W_hid fused)
#define NG 72      // gemm blocks (NC/32)
#define SLOT 16    // flag padding: 16 uints = 64B

#define ALOAD32(p)     __hip_atomic_load((const unsigned*)(p), __ATOMIC_RELAXED, __HIP_MEMORY_SCOPE_AGENT)
#define ALOAD64(p)     __hip_atomic_load((const ull*)(p), __ATOMIC_RELAXED, __HIP_MEMORY_SCOPE_AGENT)
#define ALOADF(p)      __hip_atomic_load((const float*)(p), __ATOMIC_RELAXED, __HIP_MEMORY_SCOPE_AGENT)
#define ASTORE32(p, v) __hip_atomic_store((unsigned*)(p), (v), __ATOMIC_RELAXED, __HIP_MEMORY_SCOPE_AGENT)
#define ASTOREF(p, v)  __hip_atomic_store((float*)(p), (v), __ATOMIC_RELAXED, __HIP_MEMORY_SCOPE_AGENT)

// ---------------------------------------------------------------- converts
__global__ void k_cvt_f16(const float* __restrict__ x, f16* __restrict__ y, int n4) {
    int i = blockIdx.x * 256 + threadIdx.x;
    if (i < n4) {
        float4 v = ((const float4*)x)[i];
        f16x4 h = {(f16)v.x, (f16)v.y, (f16)v.z, (f16)v.w};
        ((f16x4*)y)[i] = h;
    }
}

// transpose+convert: x f32 [R][C] -> y f16 [C][R]
__global__ void k_tcvt(const float* __restrict__ x, f16* __restrict__ y, int R, int C) {
    __shared__ float ls[32][33];
    int c0 = blockIdx.x * 32, r0 = blockIdx.y * 32;
    int tid = threadIdx.x;
    int rr = tid >> 3, cs = (tid & 7) * 4;
    float4 v = *(const float4*)&x[(size_t)(r0 + rr) * C + c0 + cs];
    ls[rr][cs] = v.x; ls[rr][cs + 1] = v.y; ls[rr][cs + 2] = v.z; ls[rr][cs + 3] = v.w;
    __syncthreads();
    int cr = tid >> 3, rs = (tid & 7) * 4;
    f16x4 o = {(f16)ls[rs][cr], (f16)ls[rs + 1][cr], (f16)ls[rs + 2][cr], (f16)ls[rs + 3][cr]};
    *(f16x4*)&y[(size_t)(c0 + cr) * R + r0 + rs] = o;
}

// embedding gather -> fp16, row r = b*T + t
__global__ void k_emb(const float* __restrict__ emb, const int* __restrict__ cap,
                      f16* __restrict__ out) {
    int r = blockIdx.x;
    int tok = cap[r];
    out[(size_t)r * E_ + threadIdx.x] = (f16)emb[(size_t)tok * E_ + threadIdx.x];
}

// ---------------------------------------------------------------- init h0/c0
__global__ void k_init(const float* __restrict__ feats,
                       const float* __restrict__ Wh, const float* __restrict__ bh,
                       const float* __restrict__ Wc, const float* __restrict__ bc,
                       float* __restrict__ hbuf0, float* __restrict__ c_cur) {
    __shared__ float mean[F_];
    int b = blockIdx.x, tid = threadIdx.x;
    for (int f = tid; f < F_; f += 256) {
        float s = 0.f;
        for (int l = 0; l < L_; ++l) s += feats[((size_t)b * L_ + l) * F_ + f];
        mean[f] = s * (1.f / 49.f);
    }
    __syncthreads();
    for (int h = tid; h < H_; h += 256) {
        float a = bh[h], c = bc[h];
        for (int k = 0; k < F_; ++k) {
            float m = mean[k];
            a += m * Wh[k * H_ + h];
            c += m * Wc[k * H_ + h];
        }
        hbuf0[b * H_ + h] = a;
        c_cur[b * H_ + h] = c;
    }
}

// ---------------------------------------------------------------- feat_proj (fp32)
__global__ void k_featproj(const float* __restrict__ feats, const float* __restrict__ Wf,
                           const float* __restrict__ bf, float* __restrict__ out) {
    __shared__ float fs[16][F_];
    int r0 = blockIdx.x * 16, tid = threadIdx.x;
    for (int i = tid; i < 16 * F_; i += 256)
        fs[i >> 9][i & 511] = feats[(size_t)r0 * F_ + i];
    __syncthreads();
    float acc[16];
#pragma unroll
    for (int r = 0; r < 16; ++r) acc[r] = 0.f;
    for (int k = 0; k < F_; ++k) {
        float w = Wf[k * A_ + tid];
#pragma unroll
        for (int r = 0; r < 16; ++r) acc[r] += fs[r][k] * w;
    }
    float bb = bf[tid];
#pragma unroll
    for (int r = 0; r < 16; ++r) out[(size_t)(r0 + r) * A_ + tid] = acc[r] + bb;
}

// ---------------------------------------------------------------- 128x128 MFMA GEMM
// MODE 0: C f32 [rr*ldc+cc] + bias   MODE 1: C f16 gate-permuted [(rr*512+(cc&511))*4+(cc>>9)]
struct Smem128 { f16 As[128][40]; f16 Bs[128][40]; };

template <int MODE>
__global__ __launch_bounds__(256) void k_gemm128(
    const f16* __restrict__ A, int lda, const f16* __restrict__ Bt, int ldb,
    void* __restrict__ Cv, int ldc, int M, int K, int mtiles,
    const float* __restrict__ bias0, const float* __restrict__ bias1) {
    __shared__ Smem128 sm;
    int bid = blockIdx.x;
    int m0 = (bid % mtiles) * 128, n0 = (bid / mtiles) * 128;
    int tid = threadIdx.x, lane = tid & 63, wave = tid >> 6;
    int wr = (wave >> 1) * 64, wc = (wave & 1) * 64;
    int frow = lane & 15, fk = (lane >> 4) * 8;
    int ra = tid >> 2, ka = (tid & 3) * 8;
    f32x4 acc[4][4];
#pragma unroll
    for (int i = 0; i < 4; ++i)
#pragma unroll
        for (int j = 0; j < 4; ++j) { acc[i][j][0]=0.f; acc[i][j][1]=0.f; acc[i][j][2]=0.f; acc[i][j][3]=0.f; }

    for (int k0 = 0; k0 < K; k0 += 32) {
        f16x8 a0 = *(const f16x8*)&A[(size_t)(m0 + ra) * lda + k0 + ka];
        f16x8 a1 = *(const f16x8*)&A[(size_t)(m0 + 64 + ra) * lda + k0 + ka];
        f16x8 b0 = *(const f16x8*)&Bt[(size_t)(n0 + ra) * ldb + k0 + ka];
        f16x8 b1 = *(const f16x8*)&Bt[(size_t)(n0 + 64 + ra) * ldb + k0 + ka];
        __syncthreads();
        *(f16x8*)&sm.As[ra][ka] = a0;
        *(f16x8*)&sm.As[64 + ra][ka] = a1;
        *(f16x8*)&sm.Bs[ra][ka] = b0;
        *(f16x8*)&sm.Bs[64 + ra][ka] = b1;
        __syncthreads();
        f16x8 av[4], bv[4];
#pragma unroll
        for (int i = 0; i < 4; ++i) {
            av[i] = *(f16x8*)&sm.As[wr + i * 16 + frow][fk];
            bv[i] = *(f16x8*)&sm.Bs[wc + i * 16 + frow][fk];
        }
#pragma unroll
        for (int mi = 0; mi < 4; ++mi)
#pragma unroll
            for (int ni = 0; ni < 4; ++ni)
                acc[mi][ni] = __builtin_amdgcn_mfma_f32_16x16x32_f16(av[mi], bv[ni], acc[mi][ni], 0, 0, 0);
    }
    int rq = (lane >> 4) * 4;
#pragma unroll
    for (int mi = 0; mi < 4; ++mi)
#pragma unroll
        for (int ni = 0; ni < 4; ++ni) {
            int cc = n0 + wc + ni * 16 + frow;
            float badd = (bias0 ? bias0[cc] : 0.f) + (bias1 ? bias1[cc] : 0.f);
#pragma unroll
            for (int r = 0; r < 4; ++r) {
                int rr = m0 + wr + mi * 16 + rq + r;
                if (rr < M) {
                    if (MODE == 0)
                        ((float*)Cv)[(size_t)rr * ldc + cc] = acc[mi][ni][r] + badd;
                    else
                        ((f16*)Cv)[((size_t)rr * 512 + (cc & 511)) * 4 + (cc >> 9)] =
                            (f16)(acc[mi][ni][r] + badd);
                }
            }
        }
}

// ---------------------------------------------------------------- persistent recurrence
// 64 gate blocks (attention+softmax+gates per batch) + 72 gemm blocks
// (h @ [W_hh | W_hid] per 32-col slice, LDS-resident weights).
struct GateSm {
    float fp[L_][A_];    // 50176 B
    float ea[A_];        // 1 KB
    float ws[A_];        // 1 KB
    float sc[64];
    float alpha[64];
};                       // ~52.5 KB
struct GemmSm {
    f16 w[32][512];      // 32 KB,  16B-chunk XOR swizzle by (row&7)
    f16 hs[64][512];     // 64 KB,  same swizzle -> conflict-free b128 reads
};                       // 96 KB

__device__ __forceinline__ void wait_flags(const unsigned* flags, int n, unsigned target) {
    int l = threadIdx.x & 63;
    for (int base = 0; base < n; base += 64) {
        int idx = base + l;
        if (idx < n) {
            const unsigned* p = flags + idx * SLOT;
            int spins = 0;
            while (ALOAD32(p) < target) {
                if (++spins > 16) __builtin_amdgcn_s_sleep(1);
            }
        }
    }
    asm volatile("" ::: "memory");   // keep data loads after the poll
}

__device__ __forceinline__ float sigm(float x) { return 1.f / (1.f + __expf(-x)); }
__device__ __forceinline__ float tanh_f(float x) { return 1.f - 2.f / (1.f + __expf(2.f * x)); }

__global__ __launch_bounds__(256, 1) void k_steps(
    const f16* __restrict__ WbigT, const float* __restrict__ featproj,
    const float* __restrict__ b_hid,
    const float* __restrict__ W_score, const float* __restrict__ b_score,
    const f16* __restrict__ embprojP, const f16* __restrict__ featproj2P,
    const float* __restrict__ hbuf0, const float* __restrict__ c_cur,
    unsigned* __restrict__ hstage, f16* __restrict__ h16log,
    float* __restrict__ hwbuf, float* __restrict__ eabuf,
    float* __restrict__ out_alpha,
    unsigned* __restrict__ gateflag, unsigned* __restrict__ gemmflag) {
    __shared__ __align__(16) char smraw[sizeof(GemmSm)];
    int bid = blockIdx.x, tid = threadIdx.x;

    if (bid < 64) {
        // ============ gate/attention block for batch b ============
        int b = bid;
        GateSm* S = (GateSm*)smraw;
        for (int i = tid; i < L_ * A_; i += 256)
            ((float*)S->fp)[i] = featproj[(size_t)b * L_ * A_ + i];
        S->ws[tid] = W_score[tid];
        float bhid_r = b_hid[tid];
        float bsc = b_score[0];
        int j0 = 2 * tid;
        float c0 = c_cur[b * H_ + j0], c1 = c_cur[b * H_ + j0 + 1];
        {   // publish h0 as packed f16 pairs
            union { f16 h[2]; unsigned u; } pk;
            pk.h[0] = (f16)hbuf0[b * H_ + j0];
            pk.h[1] = (f16)hbuf0[b * H_ + j0 + 1];
            ASTORE32(hstage + (size_t)b * 256 + tid, pk.u);
        }
        __syncthreads();
        if (tid == 0) ASTORE32(&gateflag[b * SLOT], 1u);

        int wv = tid >> 6, ln = tid & 63;

        for (int t = 0; t < T_; ++t) {
            // ---- wait h@[Whh|Whid] for this step ----
            wait_flags(gemmflag, NG, (unsigned)(t + 1));
            // ---- ea into LDS (+bias) ----
            S->ea[tid] = ALOADF(&eabuf[b * 256 + tid]) + bhid_r;
            __syncthreads();
            // ---- scores ----
            for (int l = wv; l < L_; l += 4) {
                float p = 0.f;
#pragma unroll
                for (int q = 0; q < 4; ++q) {
                    int j = ln + q * 64;
                    p += tanh_f(S->fp[l][j] + S->ea[j]) * S->ws[j];
                }
#pragma unroll
                for (int off = 32; off > 0; off >>= 1) p += __shfl_xor(p, off);
                if (ln == 0) S->sc[l] = p;
            }
            __syncthreads();
            // ---- softmax (wave 0) ----
            if (tid < 64) {
                float v = (tid < L_) ? S->sc[tid] + bsc : -3.4e38f;
                float m = v;
#pragma unroll
                for (int off = 32; off > 0; off >>= 1) m = fmaxf(m, __shfl_xor(m, off));
                float e = (tid < L_) ? __expf(v - m) : 0.f;
                float s = e;
#pragma unroll
                for (int off = 32; off > 0; off >>= 1) s += __shfl_xor(s, off);
                if (tid < L_) {
                    float al = e / s;
                    S->alpha[tid] = al;
                    out_alpha[((size_t)b * T_ + t) * L_ + tid] = al;
                }
            }
            __syncthreads();
            // ---- gates + pointwise; thread owns h-cols j0, j0+1 (pcols 8tid..8tid+7) ----
            {
                const float* hwp = &hwbuf[(size_t)b * G4 + 8 * tid];
                ull v0 = ALOAD64(hwp);
                ull v1 = ALOAD64(hwp + 2);
                ull v2 = ALOAD64(hwp + 4);
                ull v3 = ALOAD64(hwp + 6);
                float2 p0 = *(float2*)&v0, p1 = *(float2*)&v1;
                float2 p2 = *(float2*)&v2, p3 = *(float2*)&v3;
                f16x8 ep = *(const f16x8*)&embprojP[(((size_t)b * T_ + t) * 512 + j0) * 4];
                float gi0 = p0.x + (float)ep[0], gf0 = p0.y + (float)ep[1];
                float gg0 = p1.x + (float)ep[2], go0 = p1.y + (float)ep[3];
                float gi1 = p2.x + (float)ep[4], gf1 = p2.y + (float)ep[5];
                float gg1 = p3.x + (float)ep[6], go1 = p3.y + (float)ep[7];
                const f16* fpb = featproj2P + ((size_t)b * L_) * G4 + j0 * 4;
#pragma unroll 16
                for (int l = 0; l < L_; ++l) {
                    float a = S->alpha[l];
                    f16x8 fv = *(const f16x8*)&fpb[(size_t)l * G4];
                    gi0 += a * (float)fv[0]; gf0 += a * (float)fv[1];
                    gg0 += a * (float)fv[2]; go0 += a * (float)fv[3];
                    gi1 += a * (float)fv[4]; gf1 += a * (float)fv[5];
                    gg1 += a * (float)fv[6]; go1 += a * (float)fv[7];
                }
                float cn0 = sigm(gf0) * c0 + sigm(gi0) * tanh_f(gg0);
                float cn1 = sigm(gf1) * c1 + sigm(gi1) * tanh_f(gg1);
                float hn0 = sigm(go0) * tanh_f(cn0);
                float hn1 = sigm(go1) * tanh_f(cn1);
                c0 = cn0; c1 = cn1;
                union { f16 h[2]; unsigned u; } pk;
                pk.h[0] = (f16)hn0; pk.h[1] = (f16)hn1;
                ASTORE32(hstage + (size_t)b * 256 + tid, pk.u);
                ((unsigned*)h16log)[((size_t)b * T_ + t) * 256 + tid] = pk.u;
            }
            __syncthreads();   // drains vmcnt: h stores at coherence point
            if (tid == 0)
                ASTORE32(&gateflag[b * SLOT], (unsigned)(t + 2));
        }
    } else {
        // ============ gemm block: 32-col slice of [W_hh | W_hid] ============
        int g = bid - 64;
        int n0 = g * 32;
        GemmSm* S = (GemmSm*)smraw;
        // stage weight slice into LDS with 16B-chunk XOR swizzle by (row&7)
        for (int idx = tid; idx < 32 * 64; idx += 256) {
            int r = idx >> 6, s = idx & 63;
            *(f16x8*)&S->w[r][(s ^ (r & 7)) * 8] =
                *(const f16x8*)&WbigT[(size_t)(n0 + r) * H_ + s * 8];
        }
        __syncthreads();
        int wv = tid >> 6, lane = tid & 63;
        int frow = lane & 15, q = lane >> 4;
        int mbase = (wv >> 1) * 32, nt = (wv & 1) * 16;
        int col = n0 + nt + frow;
        int rq = q * 4;
        int row_a0 = mbase + frow, row_a1 = mbase + 16 + frow, row_b = nt + frow;
        int sw_a0 = row_a0 & 7, sw_a1 = row_a1 & 7, sw_b = row_b & 7;

        for (int t = 0; t < T_; ++t) {
            wait_flags(gateflag, 64, (unsigned)(t + 1));
            // stage h (64x512 f16 = 8192 ull) via wide agent loads
            {
                const ull* hsrc = (const ull*)hstage;
#pragma unroll 16
                for (int i = 0; i < 32; ++i) {
                    int idx = i * 256 + tid;
                    int row = idx >> 7, cpair = idx & 127;
                    ull v = ALOAD64(hsrc + idx);
                    *(ull*)&S->hs[row][((cpair >> 1) ^ (row & 7)) * 8 + (cpair & 1) * 4] = v;
                }
            }
            __syncthreads();
            f32x4 acc0 = {0.f, 0.f, 0.f, 0.f}, acc1 = {0.f, 0.f, 0.f, 0.f};
#pragma unroll
            for (int kk = 0; kk < 16; ++kk) {
                int ch = kk * 4 + q;
                f16x8 av0 = *(f16x8*)&S->hs[row_a0][(ch ^ sw_a0) * 8];
                f16x8 av1 = *(f16x8*)&S->hs[row_a1][(ch ^ sw_a1) * 8];
                f16x8 bv  = *(f16x8*)&S->w[row_b][(ch ^ sw_b) * 8];
                acc0 = __builtin_amdgcn_mfma_f32_16x16x32_f16(av0, bv, acc0, 0, 0, 0);
                acc1 = __builtin_amdgcn_mfma_f32_16x16x32_f16(av1, bv, acc1, 0, 0, 0);
            }
            if (col < G4) {
                int pcol = (col & 511) * 4 + (col >> 9);
#pragma unroll
                for (int r = 0; r < 4; ++r) {
                    ASTOREF(&hwbuf[(size_t)(mbase + rq + r) * G4 + pcol], acc0[r]);
                    ASTOREF(&hwbuf[(size_t)(mbase + 16 + rq + r) * G4 + pcol], acc1[r]);
                }
            } else {
                int ac = col - G4;
#pragma unroll
                for (int r = 0; r < 4; ++r) {
                    ASTOREF(&eabuf[(size_t)(mbase + rq + r) * 256 + ac], acc0[r]);
                    ASTOREF(&eabuf[(size_t)(mbase + 16 + rq + r) * 256 + ac], acc1[r]);
                }
            }
            __syncthreads();   // drains vmcnt: hw/ea stores visible
            if (tid == 0)
                ASTORE32(&gemmflag[g * SLOT], (unsigned)(t + 1));
        }
    }
}

// ---------------------------------------------------------------- launch
extern "C" void kernel_launch(void* const* d_in, const int* in_sizes, int n_in,
                              void* d_out, int out_size, void* d_ws, size_t ws_size,
                              hipStream_t stream) {
    const float* image_feats = (const float*)d_in[0];
    const int*   caption     = (const int*)d_in[1];
    const float* embedding   = (const float*)d_in[2];
    const float* W_init_h    = (const float*)d_in[3];
    const float* b_init_h    = (const float*)d_in[4];
    const float* W_init_c    = (const float*)d_in[5];
    const float* b_init_c    = (const float*)d_in[6];
    const float* W_feat      = (const float*)d_in[7];
    const float* b_feat      = (const float*)d_in[8];
    const float* W_hid       = (const float*)d_in[9];
    const float* b_hid       = (const float*)d_in[10];
    const float* W_score     = (const float*)d_in[11];
    const float* b_score     = (const float*)d_in[12];
    const float* W_ih        = (const float*)d_in[13];
    const float* b_ih        = (const float*)d_in[14];
    const float* W_hh        = (const float*)d_in[15];
    const float* b_hh        = (const float*)d_in[16];
    const float* W_out       = (const float*)d_in[17];
    const float* b_out       = (const float*)d_in[18];

    float* preds = (float*)d_out;                                   // (B,T,V)
    float* out_alpha = preds + (size_t)B_ * T_ * V_;                // (B,T,L)

    size_t off = 0;
    char* base = (char*)d_ws;
    auto carve = [&](size_t bytes) {
        void* p = base + off;
        off += (bytes + 255) & ~(size_t)255;
        return p;
    };
    const int MP = 3200;  // B*L=3136 padded to 25*128
    f16* featproj2P = (f16*)carve((size_t)MP * G4 * 2);             // 13.1 MB
    f16* embprojP   = (f16*)carve((size_t)B_ * T_ * G4 * 2);        // 8.4 MB
    float* featproj = (float*)carve((size_t)B_ * L_ * A_ * 4);      // 3.2 MB
    float* hbuf0    = (float*)carve((size_t)B_ * H_ * 4);
    float* c_cur    = (float*)carve((size_t)B_ * H_ * 4);
    float* hwbuf    = (float*)carve((size_t)B_ * G4 * 4);           // 512 KB
    float* eabuf    = (float*)carve((size_t)B_ * A_ * 4);           // 64 KB
    unsigned* hstage = (unsigned*)carve((size_t)B_ * 256 * 4);      // 64 KB
    unsigned* flags = (unsigned*)carve((64 + NG) * SLOT * 4);
    f16* feats16    = (f16*)carve((size_t)MP * F_ * 2);
    f16* embs16     = (f16*)carve((size_t)B_ * T_ * E_ * 2);
    f16* WihT       = (f16*)carve((size_t)G4 * (E_ + F_) * 2);
    f16* WbigT      = (f16*)carve((size_t)NC * H_ * 2);             // [2304][512]
    f16* WoutT      = (f16*)carve((size_t)V_ * H_ * 2);
    f16* h16log     = (f16*)carve((size_t)B_ * T_ * H_ * 2);
    unsigned* gateflag = flags;
    unsigned* gemmflag = flags + 64 * SLOT;
    (void)ws_size; (void)in_sizes; (void)n_in; (void)out_size;

    hipLaunchKernelGGL(k_tcvt, dim3(G4 / 32, (E_ + F_) / 32), dim3(256), 0, stream,
                       W_ih, WihT, E_ + F_, G4);
    hipLaunchKernelGGL(k_tcvt, dim3(G4 / 32, H_ / 32), dim3(256), 0, stream,
                       W_hh, WbigT, H_, G4);
    hipLaunchKernelGGL(k_tcvt, dim3(A_ / 32, H_ / 32), dim3(256), 0, stream,
                       W_hid, WbigT + (size_t)G4 * H_, H_, A_);
    hipLaunchKernelGGL(k_tcvt, dim3(V_ / 32, H_ / 32), dim3(256), 0, stream,
                       W_out, WoutT, H_, V_);
    {
        int n4 = (int)((size_t)B_ * L_ * F_ / 4);
        hipLaunchKernelGGL(k_cvt_f16, dim3((n4 + 255) / 256), dim3(256), 0, stream,
                           image_feats, feats16, n4);
    }
    hipLaunchKernelGGL(k_emb, dim3(B_ * T_), dim3(E_), 0, stream, embedding, caption, embs16);
    hipLaunchKernelGGL(k_init, dim3(B_), dim3(256), 0, stream,
                       image_feats, W_init_h, b_init_h, W_init_c, b_init_c,
                       hbuf0, c_cur);
    hipLaunchKernelGGL(k_featproj, dim3(B_ * L_ / 16), dim3(256), 0, stream,
                       image_feats, W_feat, b_feat, featproj);
    // featproj2P (f16, gate-permuted) = feats @ W_ih[E:,:]
    hipLaunchKernelGGL(HIP_KERNEL_NAME(k_gemm128<1>), dim3(25 * (G4 / 128)), dim3(256), 0, stream,
                       feats16, F_, WihT + E_, E_ + F_,
                       (void*)featproj2P, G4, MP, F_, 25,
                       (const float*)nullptr, (const float*)nullptr);
    // embprojP (f16, gate-permuted) = embs @ W_ih[:E,:] + b_ih + b_hh
    hipLaunchKernelGGL(HIP_KERNEL_NAME(k_gemm128<1>), dim3((B_ * T_ / 128) * (G4 / 128)), dim3(256), 0, stream,
                       embs16, E_, WihT, E_ + F_,
                       (void*)embprojP, G4, B_ * T_, E_, B_ * T_ / 128,
                       b_ih, b_hh);
    // persistent recurrence: 64 gate + 72 gemm blocks, fence-free flag handoff
    hipMemsetAsync(flags, 0, (64 + NG) * SLOT * 4, stream);
    hipLaunchKernelGGL(k_steps, dim3(64 + NG), dim3(256), 0, stream,
                       WbigT, featproj, b_hid, W_score, b_score,
                       embprojP, featproj2P, hbuf0, c_cur,
                       hstage, h16log, hwbuf, eabuf, out_alpha, gateflag, gemmflag);
    // predictions = h16log @ W_out + b_out
    hipLaunchKernelGGL(HIP_KERNEL_NAME(k_gemm128<0>), dim3((B_ * T_ / 128) * (V_ / 128)), dim3(256), 0, stream,
                       h16log, H_, WoutT, H_,
                       (void*)preds, V_, B_ * T_, H_, B_ * T_ / 128,
                       b_out, (const float*)nullptr);
}

// Round 6
// 841.027 us; speedup vs baseline: 1.2109x; 1.2109x over previous
//
#include <hip/hip_runtime.h>
#include <hip/hip_bf16.h>

typedef _Float16 f16;
typedef _Float16 f16x8 __attribute__((ext_vector_type(8)));
typedef _Float16 f16x4 __attribute__((ext_vector_type(4)));
typedef _Float16 f16x2 __attribute__((ext_vector_type(2)));
typedef float f32x4 __attribute__((ext_vector_type(4)));
typedef unsigned long long ull;

#define B_ 64
#define T_ 32
#define L_ 49
#define F_ 512
#define H_ 512
#define A_ 256
#define E_ 256
#define V_ 32000
#define G4 2048    // 4*H
#define NG 32      // gemm blocks (64 cols each)
#define SLOT 16    // flag padding: 16 uints = 64B

#define ALOAD32(p)     __hip_atomic_load((const unsigned*)(p), __ATOMIC_RELAXED, __HIP_MEMORY_SCOPE_AGENT)
#define ASTORE32(p, v) __hip_atomic_store((unsigned*)(p), (v), __ATOMIC_RELAXED, __HIP_MEMORY_SCOPE_AGENT)
#define ASTOREF(p, v)  __hip_atomic_store((float*)(p), (v), __ATOMIC_RELAXED, __HIP_MEMORY_SCOPE_AGENT)

// ---------------------------------------------------------------- converts
__global__ void k_cvt_f16(const float* __restrict__ x, f16* __restrict__ y, int n4) {
    int i = blockIdx.x * 256 + threadIdx.x;
    if (i < n4) {
        float4 v = ((const float4*)x)[i];
        f16x4 h = {(f16)v.x, (f16)v.y, (f16)v.z, (f16)v.w};
        ((f16x4*)y)[i] = h;
    }
}

// transpose+convert: x f32 [R][C] -> y f16 [C][R]
__global__ void k_tcvt(const float* __restrict__ x, f16* __restrict__ y, int R, int C) {
    __shared__ float ls[32][33];
    int c0 = blockIdx.x * 32, r0 = blockIdx.y * 32;
    int tid = threadIdx.x;
    int rr = tid >> 3, cs = (tid & 7) * 4;
    float4 v = *(const float4*)&x[(size_t)(r0 + rr) * C + c0 + cs];
    ls[rr][cs] = v.x; ls[rr][cs + 1] = v.y; ls[rr][cs + 2] = v.z; ls[rr][cs + 3] = v.w;
    __syncthreads();
    int cr = tid >> 3, rs = (tid & 7) * 4;
    f16x4 o = {(f16)ls[rs][cr], (f16)ls[rs + 1][cr], (f16)ls[rs + 2][cr], (f16)ls[rs + 3][cr]};
    *(f16x4*)&y[(size_t)(c0 + cr) * R + r0 + rs] = o;
}

// W_hid f32 [512][256] -> k-pair packed f16x2 [256][256]
__global__ void k_pairs(const float* __restrict__ w, f16* __restrict__ out) {
    int k2 = blockIdx.x, a = threadIdx.x;
    out[(k2 * 256 + a) * 2]     = (f16)w[(2 * k2) * 256 + a];
    out[(k2 * 256 + a) * 2 + 1] = (f16)w[(2 * k2 + 1) * 256 + a];
}

// embedding gather -> fp16, row r = b*T + t
__global__ void k_emb(const float* __restrict__ emb, const int* __restrict__ cap,
                      f16* __restrict__ out) {
    int r = blockIdx.x;
    int tok = cap[r];
    out[(size_t)r * E_ + threadIdx.x] = (f16)emb[(size_t)tok * E_ + threadIdx.x];
}

// ---------------------------------------------------------------- init h0/c0
__global__ void k_init(const float* __restrict__ feats,
                       const float* __restrict__ Wh, const float* __restrict__ bh,
                       const float* __restrict__ Wc, const float* __restrict__ bc,
                       float* __restrict__ hbuf0, float* __restrict__ c_cur) {
    __shared__ float mean[F_];
    int b = blockIdx.x, tid = threadIdx.x;
    for (int f = tid; f < F_; f += 256) {
        float s = 0.f;
        for (int l = 0; l < L_; ++l) s += feats[((size_t)b * L_ + l) * F_ + f];
        mean[f] = s * (1.f / 49.f);
    }
    __syncthreads();
    for (int h = tid; h < H_; h += 256) {
        float a = bh[h], c = bc[h];
        for (int k = 0; k < F_; ++k) {
            float m = mean[k];
            a += m * Wh[k * H_ + h];
            c += m * Wc[k * H_ + h];
        }
        hbuf0[b * H_ + h] = a;
        c_cur[b * H_ + h] = c;
    }
}

// ---------------------------------------------------------------- feat_proj (fp32)
__global__ void k_featproj(const float* __restrict__ feats, const float* __restrict__ Wf,
                           const float* __restrict__ bf, float* __restrict__ out) {
    __shared__ float fs[16][F_];
    int r0 = blockIdx.x * 16, tid = threadIdx.x;
    for (int i = tid; i < 16 * F_; i += 256)
        fs[i >> 9][i & 511] = feats[(size_t)r0 * F_ + i];
    __syncthreads();
    float acc[16];
#pragma unroll
    for (int r = 0; r < 16; ++r) acc[r] = 0.f;
    for (int k = 0; k < F_; ++k) {
        float w = Wf[k * A_ + tid];
#pragma unroll
        for (int r = 0; r < 16; ++r) acc[r] += fs[r][k] * w;
    }
    float bb = bf[tid];
#pragma unroll
    for (int r = 0; r < 16; ++r) out[(size_t)(r0 + r) * A_ + tid] = acc[r] + bb;
}

// ---------------------------------------------------------------- 128x128 MFMA GEMM
// MODE 0: C f32 [rr*ldc+cc] + bias
// MODE 1: C f16 gate-permuted [(rr*512+(cc&511))*4+(cc>>9)]
// MODE 2: C f32, input rows rr = t*64+b, output row remap -> (b*T+t)
struct Smem128 { f16 As[128][40]; f16 Bs[128][40]; };

template <int MODE>
__global__ __launch_bounds__(256) void k_gemm128(
    const f16* __restrict__ A, int lda, const f16* __restrict__ Bt, int ldb,
    void* __restrict__ Cv, int ldc, int M, int K, int mtiles,
    const float* __restrict__ bias0, const float* __restrict__ bias1) {
    __shared__ Smem128 sm;
    int bid = blockIdx.x;
    int m0 = (bid % mtiles) * 128, n0 = (bid / mtiles) * 128;
    int tid = threadIdx.x, lane = tid & 63, wave = tid >> 6;
    int wr = (wave >> 1) * 64, wc = (wave & 1) * 64;
    int frow = lane & 15, fk = (lane >> 4) * 8;
    int ra = tid >> 2, ka = (tid & 3) * 8;
    f32x4 acc[4][4];
#pragma unroll
    for (int i = 0; i < 4; ++i)
#pragma unroll
        for (int j = 0; j < 4; ++j) { acc[i][j][0]=0.f; acc[i][j][1]=0.f; acc[i][j][2]=0.f; acc[i][j][3]=0.f; }

    for (int k0 = 0; k0 < K; k0 += 32) {
        f16x8 a0 = *(const f16x8*)&A[(size_t)(m0 + ra) * lda + k0 + ka];
        f16x8 a1 = *(const f16x8*)&A[(size_t)(m0 + 64 + ra) * lda + k0 + ka];
        f16x8 b0 = *(const f16x8*)&Bt[(size_t)(n0 + ra) * ldb + k0 + ka];
        f16x8 b1 = *(const f16x8*)&Bt[(size_t)(n0 + 64 + ra) * ldb + k0 + ka];
        __syncthreads();
        *(f16x8*)&sm.As[ra][ka] = a0;
        *(f16x8*)&sm.As[64 + ra][ka] = a1;
        *(f16x8*)&sm.Bs[ra][ka] = b0;
        *(f16x8*)&sm.Bs[64 + ra][ka] = b1;
        __syncthreads();
        f16x8 av[4], bv[4];
#pragma unroll
        for (int i = 0; i < 4; ++i) {
            av[i] = *(f16x8*)&sm.As[wr + i * 16 + frow][fk];
            bv[i] = *(f16x8*)&sm.Bs[wc + i * 16 + frow][fk];
        }
#pragma unroll
        for (int mi = 0; mi < 4; ++mi)
#pragma unroll
            for (int ni = 0; ni < 4; ++ni)
                acc[mi][ni] = __builtin_amdgcn_mfma_f32_16x16x32_f16(av[mi], bv[ni], acc[mi][ni], 0, 0, 0);
    }
    int rq = (lane >> 4) * 4;
#pragma unroll
    for (int mi = 0; mi < 4; ++mi)
#pragma unroll
        for (int ni = 0; ni < 4; ++ni) {
            int cc = n0 + wc + ni * 16 + frow;
            float badd = (bias0 ? bias0[cc] : 0.f) + (bias1 ? bias1[cc] : 0.f);
#pragma unroll
            for (int r = 0; r < 4; ++r) {
                int rr = m0 + wr + mi * 16 + rq + r;
                if (rr < M) {
                    if (MODE == 0)
                        ((float*)Cv)[(size_t)rr * ldc + cc] = acc[mi][ni][r] + badd;
                    else if (MODE == 1)
                        ((f16*)Cv)[((size_t)rr * 512 + (cc & 511)) * 4 + (cc >> 9)] =
                            (f16)(acc[mi][ni][r] + badd);
                    else
                        ((float*)Cv)[((size_t)(rr & 63) * T_ + (rr >> 6)) * ldc + cc] =
                            acc[mi][ni][r] + badd;
                }
            }
        }
}

// ---------------------------------------------------------------- persistent recurrence
// 64 gate blocks (attention + softmax + gates, per batch) run CONCURRENTLY with
// 32 gemm blocks (h @ W_hh, 64-col LDS-resident slices). Handoff: sc1 flag +
// sc1 producer stores; consumers use PLAIN cached loads on per-step slabs
// (fresh addresses each step -> no stale lines; replay values identical).
struct GateSm {
    float fp[L_][A_];    // 50176 B
    float h[H_];
    float ea[A_];
    float ws[A_];
    float sc[64];
    float alpha[64];
};
struct GemmSm {
    f16 w[64][512];      // 64 KB, 16B-chunk XOR swizzle by (row&7)
    f16 hs[64][512];     // 64 KB, same swizzle
};                       // 128 KB

__device__ __forceinline__ void wait_n(const unsigned* flags, int n, unsigned target) {
    int l = threadIdx.x & 63;
    if (l < n) {
        const unsigned* p = flags + l * SLOT;
        while (ALOAD32(p) < target) __builtin_amdgcn_s_sleep(1);
    }
    asm volatile("" ::: "memory");   // keep data loads after the poll
}

__device__ __forceinline__ float sigm(float x) { return 1.f / (1.f + __expf(-x)); }
__device__ __forceinline__ float tanh_f(float x) { return 1.f - 2.f / (1.f + __expf(2.f * x)); }

__global__ __launch_bounds__(256, 1) void k_steps(
    const f16* __restrict__ WhhT, const float* __restrict__ featproj,
    const f16x2* __restrict__ Whidp, const float* __restrict__ b_hid,
    const float* __restrict__ W_score, const float* __restrict__ b_score,
    const f16* __restrict__ embprojP, const f16* __restrict__ featproj2P,
    const float* __restrict__ hbuf0, const float* __restrict__ c_cur,
    f16* __restrict__ hslab, float* __restrict__ hwslab,
    float* __restrict__ out_alpha,
    unsigned* __restrict__ gateflag, unsigned* __restrict__ gemmflag) {
    __shared__ __align__(16) char smraw[sizeof(GemmSm)];
    int bid = blockIdx.x, tid = threadIdx.x;

    if (bid < 64) {
        // ============ gate/attention block for batch b ============
        int b = bid;
        GateSm* S = (GateSm*)smraw;
        for (int i = tid; i < L_ * A_; i += 256)
            ((float*)S->fp)[i] = featproj[(size_t)b * L_ * A_ + i];
        S->ws[tid] = W_score[tid];
        float bhid_r = b_hid[tid];
        float bsc = b_score[0];
        int j0 = 2 * tid;
        float c0 = c_cur[b * H_ + j0], c1 = c_cur[b * H_ + j0 + 1];
        {   // publish h0 (slab 0) and mirror into LDS
            float h0 = hbuf0[b * H_ + j0], h1 = hbuf0[b * H_ + j0 + 1];
            S->h[j0] = h0; S->h[j0 + 1] = h1;
            union { f16 h[2]; unsigned u; } pk;
            pk.h[0] = (f16)h0; pk.h[1] = (f16)h1;
            ASTORE32((unsigned*)hslab + (size_t)b * 256 + tid, pk.u);
        }
        __syncthreads();
        if (tid == 0) ASTORE32(&gateflag[b * SLOT], 1u);

        const float2* h2 = (const float2*)S->h;
        int wv = tid >> 6, ln = tid & 63;

        for (int t = 0; t < T_; ++t) {
            // ---- ea = h @ W_hid + b_hid (local h; overlaps gemm blocks) ----
            float acc = bhid_r;
#pragma unroll 16
            for (int k2 = 0; k2 < 256; ++k2) {
                f16x2 w = Whidp[k2 * 256 + tid];
                float2 hp = h2[k2];
                acc += hp.x * (float)w.x + hp.y * (float)w.y;
            }
            S->ea[tid] = acc;
            __syncthreads();
            // ---- scores ----
            for (int l = wv; l < L_; l += 4) {
                float p = 0.f;
#pragma unroll
                for (int q = 0; q < 4; ++q) {
                    int j = ln + q * 64;
                    p += tanh_f(S->fp[l][j] + S->ea[j]) * S->ws[j];
                }
#pragma unroll
                for (int off = 32; off > 0; off >>= 1) p += __shfl_xor(p, off);
                if (ln == 0) S->sc[l] = p;
            }
            __syncthreads();
            // ---- softmax (wave 0) ----
            if (tid < 64) {
                float v = (tid < L_) ? S->sc[tid] + bsc : -3.4e38f;
                float m = v;
#pragma unroll
                for (int off = 32; off > 0; off >>= 1) m = fmaxf(m, __shfl_xor(m, off));
                float e = (tid < L_) ? __expf(v - m) : 0.f;
                float s = e;
#pragma unroll
                for (int off = 32; off > 0; off >>= 1) s += __shfl_xor(s, off);
                if (tid < L_) {
                    float al = e / s;
                    S->alpha[tid] = al;
                    out_alpha[((size_t)b * T_ + t) * L_ + tid] = al;
                }
            }
            __syncthreads();
            // ---- alpha-weighted featproj2 partial sums (no hw needed yet) ----
            float s0=0.f,s1=0.f,s2=0.f,s3=0.f,s4=0.f,s5=0.f,s6=0.f,s7=0.f;
            {
                const f16* fpb = featproj2P + (size_t)b * L_ * G4 + j0 * 4;
#pragma unroll 7
                for (int l = 0; l < L_; ++l) {
                    float a = S->alpha[l];
                    f16x8 fv = *(const f16x8*)&fpb[(size_t)l * G4];
                    s0 += a * (float)fv[0]; s1 += a * (float)fv[1];
                    s2 += a * (float)fv[2]; s3 += a * (float)fv[3];
                    s4 += a * (float)fv[4]; s5 += a * (float)fv[5];
                    s6 += a * (float)fv[6]; s7 += a * (float)fv[7];
                }
            }
            f16x8 ep = *(const f16x8*)&embprojP[(((size_t)b * T_ + t) * 512 + j0) * 4];
            // ---- wait recurrent matmul, then finish gates ----
            wait_n(gemmflag, NG, (unsigned)(t + 1));
            {
                const float2* hwp = (const float2*)(hwslab + (size_t)t * B_ * G4 + (size_t)b * G4);
                float2 vi = hwp[tid], vf = hwp[256 + tid], vg = hwp[512 + tid], vo = hwp[768 + tid];
                float gi0 = vi.x + (float)ep[0] + s0, gf0 = vf.x + (float)ep[1] + s1;
                float gg0 = vg.x + (float)ep[2] + s2, go0 = vo.x + (float)ep[3] + s3;
                float gi1 = vi.y + (float)ep[4] + s4, gf1 = vf.y + (float)ep[5] + s5;
                float gg1 = vg.y + (float)ep[6] + s6, go1 = vo.y + (float)ep[7] + s7;
                float cn0 = sigm(gf0) * c0 + sigm(gi0) * tanh_f(gg0);
                float cn1 = sigm(gf1) * c1 + sigm(gi1) * tanh_f(gg1);
                float hn0 = sigm(go0) * tanh_f(cn0);
                float hn1 = sigm(go1) * tanh_f(cn1);
                c0 = cn0; c1 = cn1;
                S->h[j0] = hn0; S->h[j0 + 1] = hn1;
                union { f16 h[2]; unsigned u; } pk;
                pk.h[0] = (f16)hn0; pk.h[1] = (f16)hn1;
                ASTORE32((unsigned*)hslab + ((size_t)(t + 1) * B_ + b) * 256 + tid, pk.u);
            }
            __syncthreads();   // barrier drains vmcnt: h stores at coherence point
            if (tid == 0)
                ASTORE32(&gateflag[b * SLOT], (unsigned)(t + 2));
        }
    } else {
        // ============ gemm block: 64-col slice of W_hh ============
        int g = bid - 64;
        int n0 = g * 64;
        GemmSm* S = (GemmSm*)smraw;
        // stage weight slice (64x512) into LDS, 16B-chunk XOR swizzle by (row&7)
        for (int i = 0; i < 16; ++i) {
            int cid = i * 256 + tid;
            int r = cid >> 6, ch = cid & 63;
            *(f16x8*)&S->w[r][(ch ^ (r & 7)) * 8] =
                *(const f16x8*)&WhhT[(size_t)(n0 + r) * H_ + ch * 8];
        }
        __syncthreads();
        int wv = tid >> 6, lane = tid & 63;
        int frow = lane & 15, q = lane >> 4;
        int sw = frow & 7;
        int rq = q * 4;
        int colg = n0 + wv * 16 + frow;

        for (int t = 0; t < T_; ++t) {
            wait_n(gateflag, 64, (unsigned)(t + 1));
            // stage h(t) (64x512 f16) via PLAIN coalesced loads (fresh slab)
            {
                const f16* hs16 = hslab + (size_t)t * B_ * H_;
#pragma unroll
                for (int i = 0; i < 16; ++i) {
                    int cid = i * 256 + tid;
                    int r = cid >> 6, ch = cid & 63;
                    *(f16x8*)&S->hs[r][(ch ^ (r & 7)) * 8] =
                        *(const f16x8*)&hs16[(size_t)r * H_ + ch * 8];
                }
            }
            __syncthreads();
            f32x4 a4[4];
#pragma unroll
            for (int mi = 0; mi < 4; ++mi) { a4[mi][0]=0.f; a4[mi][1]=0.f; a4[mi][2]=0.f; a4[mi][3]=0.f; }
#pragma unroll
            for (int kk = 0; kk < 16; ++kk) {
                int ch = ((kk * 4 + q) ^ sw) * 8;
                f16x8 bv = *(f16x8*)&S->w[wv * 16 + frow][ch];
#pragma unroll
                for (int mi = 0; mi < 4; ++mi) {
                    f16x8 av = *(f16x8*)&S->hs[mi * 16 + frow][ch];
                    a4[mi] = __builtin_amdgcn_mfma_f32_16x16x32_f16(av, bv, a4[mi], 0, 0, 0);
                }
            }
            // store hw(t) in natural [row][col] layout: full-line coalesced sc1
            {
                float* hw = hwslab + (size_t)t * B_ * G4;
#pragma unroll
                for (int mi = 0; mi < 4; ++mi)
#pragma unroll
                    for (int r = 0; r < 4; ++r)
                        ASTOREF(&hw[(size_t)(mi * 16 + rq + r) * G4 + colg], a4[mi][r]);
            }
            __syncthreads();   // barrier drains vmcnt: hw stores at coherence point
            if (tid == 0)
                ASTORE32(&gemmflag[g * SLOT], (unsigned)(t + 1));
        }
    }
}

// ---------------------------------------------------------------- launch
extern "C" void kernel_launch(void* const* d_in, const int* in_sizes, int n_in,
                              void* d_out, int out_size, void* d_ws, size_t ws_size,
                              hipStream_t stream) {
    const float* image_feats = (const float*)d_in[0];
    const int*   caption     = (const int*)d_in[1];
    const float* embedding   = (const float*)d_in[2];
    const float* W_init_h    = (const float*)d_in[3];
    const float* b_init_h    = (const float*)d_in[4];
    const float* W_init_c    = (const float*)d_in[5];
    const float* b_init_c    = (const float*)d_in[6];
    const float* W_feat      = (const float*)d_in[7];
    const float* b_feat      = (const float*)d_in[8];
    const float* W_hid       = (const float*)d_in[9];
    const float* b_hid       = (const float*)d_in[10];
    const float* W_score     = (const float*)d_in[11];
    const float* b_score     = (const float*)d_in[12];
    const float* W_ih        = (const float*)d_in[13];
    const float* b_ih        = (const float*)d_in[14];
    const float* W_hh        = (const float*)d_in[15];
    const float* b_hh        = (const float*)d_in[16];
    const float* W_out       = (const float*)d_in[17];
    const float* b_out       = (const float*)d_in[18];

    float* preds = (float*)d_out;                                   // (B,T,V)
    float* out_alpha = preds + (size_t)B_ * T_ * V_;                // (B,T,L)

    size_t off = 0;
    char* base = (char*)d_ws;
    auto carve = [&](size_t bytes) {
        void* p = base + off;
        off += (bytes + 255) & ~(size_t)255;
        return p;
    };
    const int MP = 3200;  // B*L=3136 padded to 25*128
    f16* featproj2P = (f16*)carve((size_t)MP * G4 * 2);             // 13.1 MB
    f16* embprojP   = (f16*)carve((size_t)B_ * T_ * G4 * 2);        // 8.4 MB
    float* featproj = (float*)carve((size_t)B_ * L_ * A_ * 4);      // 3.2 MB
    float* hbuf0    = (float*)carve((size_t)B_ * H_ * 4);
    float* c_cur    = (float*)carve((size_t)B_ * H_ * 4);
    float* hwslab   = (float*)carve((size_t)T_ * B_ * G4 * 4);      // 16 MB (per-step slabs)
    f16* hslab      = (f16*)carve((size_t)(T_ + 1) * B_ * H_ * 2);  // 2.1 MB (per-step slabs)
    unsigned* flags = (unsigned*)carve((64 + NG) * SLOT * 4);
    f16* feats16    = (f16*)carve((size_t)MP * F_ * 2);
    f16* embs16     = (f16*)carve((size_t)B_ * T_ * E_ * 2);
    f16* WihT       = (f16*)carve((size_t)G4 * (E_ + F_) * 2);
    f16* WhhT       = (f16*)carve((size_t)G4 * H_ * 2);
    f16* WoutT      = (f16*)carve((size_t)V_ * H_ * 2);
    f16* Whidp      = (f16*)carve((size_t)H_ * A_ * 2);
    unsigned* gateflag = flags;
    unsigned* gemmflag = flags + 64 * SLOT;
    (void)ws_size; (void)in_sizes; (void)n_in; (void)out_size;

    hipLaunchKernelGGL(k_tcvt, dim3(G4 / 32, (E_ + F_) / 32), dim3(256), 0, stream,
                       W_ih, WihT, E_ + F_, G4);
    hipLaunchKernelGGL(k_tcvt, dim3(G4 / 32, H_ / 32), dim3(256), 0, stream,
                       W_hh, WhhT, H_, G4);
    hipLaunchKernelGGL(k_tcvt, dim3(V_ / 32, H_ / 32), dim3(256), 0, stream,
                       W_out, WoutT, H_, V_);
    {
        int n4 = (int)((size_t)B_ * L_ * F_ / 4);
        hipLaunchKernelGGL(k_cvt_f16, dim3((n4 + 255) / 256), dim3(256), 0, stream,
                           image_feats, feats16, n4);
    }
    hipLaunchKernelGGL(k_pairs, dim3(256), dim3(256), 0, stream, W_hid, Whidp);
    hipLaunchKernelGGL(k_emb, dim3(B_ * T_), dim3(E_), 0, stream, embedding, caption, embs16);
    hipLaunchKernelGGL(k_init, dim3(B_), dim3(256), 0, stream,
                       image_feats, W_init_h, b_init_h, W_init_c, b_init_c,
                       hbuf0, c_cur);
    hipLaunchKernelGGL(k_featproj, dim3(B_ * L_ / 16), dim3(256), 0, stream,
                       image_feats, W_feat, b_feat, featproj);
    // featproj2P (f16, gate-permuted) = feats @ W_ih[E:,:]
    hipLaunchKernelGGL(HIP_KERNEL_NAME(k_gemm128<1>), dim3(25 * (G4 / 128)), dim3(256), 0, stream,
                       feats16, F_, WihT + E_, E_ + F_,
                       (void*)featproj2P, G4, MP, F_, 25,
                       (const float*)nullptr, (const float*)nullptr);
    // embprojP (f16, gate-permuted) = embs @ W_ih[:E,:] + b_ih + b_hh
    hipLaunchKernelGGL(HIP_KERNEL_NAME(k_gemm128<1>), dim3((B_ * T_ / 128) * (G4 / 128)), dim3(256), 0, stream,
                       embs16, E_, WihT, E_ + F_,
                       (void*)embprojP, G4, B_ * T_, E_, B_ * T_ / 128,
                       b_ih, b_hh);
    // persistent recurrence: 64 gate + 32 gemm blocks
    hipMemsetAsync(flags, 0, (64 + NG) * SLOT * 4, stream);
    hipLaunchKernelGGL(k_steps, dim3(64 + NG), dim3(256), 0, stream,
                       WhhT, featproj, (const f16x2*)Whidp, b_hid, W_score, b_score,
                       embprojP, featproj2P, hbuf0, c_cur,
                       hslab, hwslab, out_alpha, gateflag, gemmflag);
    // predictions = hslab[1..32] @ W_out + b_out  (rows t*64+b -> out row b*T+t)
    hipLaunchKernelGGL(HIP_KERNEL_NAME(k_gemm128<2>), dim3((B_ * T_ / 128) * (V_ / 128)), dim3(256), 0, stream,
                       hslab + (size_t)B_ * H_, H_, WoutT, H_,
                       (void*)preds, V_, B_ * T_, H_, B_ * T_ / 128,
                       b_out, (const float*)nullptr);
}